// Round 1
// baseline (484.844 us; speedup 1.0000x reference)
//
#include <hip/hip_runtime.h>

// ShiftingLayer: out[j] = (0 <= j-offset < n) ? x[j-offset] : 0,
// offset = trunc(w_row + row_length*w_col).
// Pure memory-bound shifted copy: 268 MB read + 268 MB write (lower bound).
//
// v2 (polish probe):
//  - 8 floats/thread, two float4 stores (fewer issue slots per byte)
//  - block-uniform interior test: all-but-boundary blocks skip per-element
//    guards entirely (offset=8193 -> ~5 of 32768 blocks take the slow path)
//  - nontemporal float4 stores: out is write-once/never-read; don't evict
//    the x stream (268 MB, just over the 256 MB L3) from L2/L3.

typedef float f4_t __attribute__((ext_vector_type(4)));

__global__ __launch_bounds__(256) void ShiftingLayer_shift_kernel(
    const float* __restrict__ x,
    const float* __restrict__ w_row,
    const float* __restrict__ w_col,
    const int*   __restrict__ row_length,
    float* __restrict__ out,
    long long n)
{
    // Scalar offset computed on-device (scalars live in 1-element arrays).
    // float->int truncates toward zero, matching astype(int32).
    const long long offset =
        (long long)(int)(w_row[0] + (float)row_length[0] * w_col[0]);

    const long long base =
        ((long long)blockIdx.x * blockDim.x + threadIdx.x) * 8;
    if (base >= n) return;

    const long long s = base - offset;

    // Block-uniform interior check: this block writes out[blk0, blk1) and
    // reads x[blk0-offset, blk1-offset). If both ranges are fully in-bounds,
    // no lane needs any guard.
    const long long blk0 = (long long)blockIdx.x * ((long long)blockDim.x * 8);
    const long long blk1 = blk0 + (long long)blockDim.x * 8;
    const bool interior =
        (blk0 - offset >= 0) && (blk1 - offset <= n) && (blk1 <= n);

    if (interior) {
        // Source is only 4B-aligned (offset=8193), so loads stay per-dword
        // (they coalesce; HBM traffic is line-granular either way).
        f4_t v0, v1;
        v0.x = x[s + 0]; v0.y = x[s + 1]; v0.z = x[s + 2]; v0.w = x[s + 3];
        v1.x = x[s + 4]; v1.y = x[s + 5]; v1.z = x[s + 6]; v1.w = x[s + 7];
        // Destination is 32B-aligned by construction: aligned dwordx4 stores.
        __builtin_nontemporal_store(v0, (f4_t*)(out + base));
        __builtin_nontemporal_store(v1, (f4_t*)(out + base + 4));
    } else {
        // Boundary blocks: fully guarded scalar path (a handful of blocks).
        #pragma unroll
        for (int k = 0; k < 8; ++k) {
            const long long j = base + k;
            if (j < n) {
                const long long ss = j - offset;
                out[j] = (ss >= 0 && ss < n) ? x[ss] : 0.0f;
            }
        }
    }
}

extern "C" void kernel_launch(void* const* d_in, const int* in_sizes, int n_in,
                              void* d_out, int out_size, void* d_ws, size_t ws_size,
                              hipStream_t stream)
{
    const float* x     = (const float*)d_in[0];
    const float* w_row = (const float*)d_in[1];
    const float* w_col = (const float*)d_in[2];
    const int*   rlen  = (const int*)d_in[3];
    float* out = (float*)d_out;

    const long long n = (long long)out_size;  // 67,108,864 elements

    const int block = 256;
    const long long chunks = (n + 7) / 8;     // 8 floats per thread
    const int grid = (int)((chunks + block - 1) / block);

    ShiftingLayer_shift_kernel<<<grid, block, 0, stream>>>(
        x, w_row, w_col, rlen, out, n);
}

// Round 2
// 426.670 us; speedup vs baseline: 1.1363x; 1.1363x over previous
//
#include <hip/hip_runtime.h>

// ShiftingLayer: out[j] = (0 <= j-offset < n) ? x[j-offset] : 0,
// offset = trunc(w_row + row_length*w_col).
// Memory-bound shifted copy: 268 MB read + 268 MB write lower bound
// (reads partially served by L3 when stores are nontemporal).
//
// v3: lane-contiguous, fully-coalesced on BOTH sides.
//  - each thread owns ONE aligned out-chunk (float4); a wave's store is one
//    contiguous, fully-covered 1 KB line run (fixes v2's half-line writes,
//    WRITE_SIZE 391 MB -> 268 MB).
//  - source realignment in registers: offset = 4q + (4-m); out-chunk t is
//    built from aligned x-chunks c=t-q and c+1 with a wave-uniform element
//    rotate m in {0..3}. Both loads are aligned dwordx4; the c+1 load is the
//    neighbor's c load -> L1 hit, no extra HBM traffic.
//  - readfirstlane scalarizes offset -> m,q,interior are SGPR, branches are
//    wave-uniform.
//  - nontemporal stores keep `out` from evicting `x` (268 MB vs 256 MB L3):
//    rocprof r1 showed FETCH 136 MB (half of x L3-resident). Keep that.

typedef float f4_t __attribute__((ext_vector_type(4)));

__global__ __launch_bounds__(256) void ShiftingLayer_shift_kernel(
    const float* __restrict__ x,
    const float* __restrict__ w_row,
    const float* __restrict__ w_col,
    const int*   __restrict__ row_length,
    float* __restrict__ out,
    long long n)
{
    // Scalar offset on-device; float->int truncates toward zero (astype int32).
    const int offset_v = (int)(w_row[0] + (float)row_length[0] * w_col[0]);
    const int offset = __builtin_amdgcn_readfirstlane(offset_v);

    const long long t = (long long)blockIdx.x * blockDim.x + threadIdx.x;
    const long long J = t * 4;               // this thread's out chunk start
    if (J >= n) return;

    // Uniform decomposition: s0 = J - offset = 4*(t-q) + m, m in [0,4).
    // (offset & 3 works for negative offsets on two's complement.)
    const int m = (4 - (offset & 3)) & 3;
    const int q = (offset + m) >> 2;         // exact division (offset+m ≡ 0 mod 4)

    // Block-uniform interior test: store range and both load chunks in-bounds
    // for every thread of this block -> no per-element guards.
    const long long t0   = (long long)blockIdx.x * blockDim.x;
    const long long tEnd = t0 + blockDim.x;
    const bool interior = (4 * tEnd <= n)
                       && (t0 - q >= 0)
                       && (4 * (tEnd - q) + 4 <= n);

    if (interior) {
        const long long c = t - q;
        const f4_t* __restrict__ x4 = (const f4_t*)x;
        const f4_t A = x4[c];                // aligned dwordx4, lane-contiguous
        f4_t v;
        if (m == 0) {
            v = A;
        } else {
            const f4_t B = x4[c + 1];        // = neighbor lane's A -> L1 hit
            if (m == 1)      v = __builtin_shufflevector(A, B, 1, 2, 3, 4);
            else if (m == 2) v = __builtin_shufflevector(A, B, 2, 3, 4, 5);
            else             v = __builtin_shufflevector(A, B, 3, 4, 5, 6);
        }
        __builtin_nontemporal_store(v, (f4_t*)(out + J));  // full-line, aligned
    } else {
        // Boundary blocks (~2 of 65536): fully guarded scalar path.
        #pragma unroll
        for (int k = 0; k < 4; ++k) {
            const long long j = J + k;
            if (j < n) {
                const long long s = j - (long long)offset;
                out[j] = (s >= 0 && s < n) ? x[s] : 0.0f;
            }
        }
    }
}

extern "C" void kernel_launch(void* const* d_in, const int* in_sizes, int n_in,
                              void* d_out, int out_size, void* d_ws, size_t ws_size,
                              hipStream_t stream)
{
    const float* x     = (const float*)d_in[0];
    const float* w_row = (const float*)d_in[1];
    const float* w_col = (const float*)d_in[2];
    const int*   rlen  = (const int*)d_in[3];
    float* out = (float*)d_out;

    const long long n = (long long)out_size;  // 67,108,864 elements

    const int block = 256;
    const long long vecs = (n + 3) / 4;       // one float4 per thread
    const int grid = (int)((vecs + block - 1) / block);

    ShiftingLayer_shift_kernel<<<grid, block, 0, stream>>>(
        x, w_row, w_col, rlen, out, n);
}